// Round 11
// baseline (252.308 us; speedup 1.0000x reference)
//
#include <hip/hip_runtime.h>
#include <hip/hip_bf16.h>

// Problem constants (fixed by setup_inputs)
#define BATCH    4
#define NPOINT   2048
#define NSUP     16384
#define NCHAN    64
#define NSAMPLE  32
#define R2       0.01f   // f32(0.1*0.1) == f32(0.01)
#define NQ       (BATCH * NPOINT)

// ---------------------------------------------------------------------------
// Kernel 1: ball query — persistent waves + dynamic query queue.
// Static 1-query-per-wave launches end on the slowest ~10% of queries
// (boundary queries scan all 16384 points; occupancy decays to a tail —
// measured 48% time-avg). Here 4096 waves stay resident and pull query ids
// from a global atomic counter, so early-exiting work rebalances and the
// VALU stays fed. Per-query body: 4x ILP + 1-deep prefetch (as round 9).
// d2 uses explicit _rn ops in reference order ((dx^2+dy^2)+dz^2) to avoid
// FMA contraction flipping borderline comparisons.
// ---------------------------------------------------------------------------
struct f3 { float x, y, z; };

__global__ __launch_bounds__(256, 4) void ball_query_kernel(
    const float* __restrict__ query,    // (B, NPOINT, 3)
    const float* __restrict__ support,  // (B, NSUP, 3)
    int* __restrict__ idx_out,          // (B*NPOINT, NSAMPLE)
    unsigned int* __restrict__ counter) // work queue head (zeroed on stream)
{
    const int lane = threadIdx.x & 63;
    const unsigned long long ltmask = (lane == 0) ? 0ull : (~0ull >> (64 - lane));

    for (;;) {
        int j = 0;
        if (lane == 0) j = (int)atomicAdd(counter, 1u);
        j = __shfl(j, 0);
        if (j >= NQ) break;                    // wave-uniform exit

        const int b = j >> 11;
        const float* qc = query + (size_t)j * 3;
        const float qx = qc[0], qy = qc[1], qz = qc[2];
        const float* sup = support + (size_t)b * NSUP * 3;
        int* out = idx_out + ((size_t)j << 5);

        int cnt = 0;
        int first = 0;

        f3 P[4], Pn[4];
#pragma unroll
        for (int u = 0; u < 4; ++u)
            P[u] = *reinterpret_cast<const f3*>(sup + (size_t)(u * 64 + lane) * 3);

        for (int base = 0; base < NSUP; base += 256) {
            const int nbase = base + 256;
            if (nbase < NSUP) {                // prefetch next group
#pragma unroll
                for (int u = 0; u < 4; ++u)
                    Pn[u] = *reinterpret_cast<const f3*>(
                        sup + (size_t)(nbase + u * 64 + lane) * 3);
            }
            unsigned long long M[4];
#pragma unroll
            for (int u = 0; u < 4; ++u) {
                const float dx = __fsub_rn(qx, P[u].x);
                const float dy = __fsub_rn(qy, P[u].y);
                const float dz = __fsub_rn(qz, P[u].z);
                const float d2 = __fadd_rn(
                    __fadd_rn(__fmul_rn(dx, dx), __fmul_rn(dy, dy)),
                    __fmul_rn(dz, dz));
                M[u] = __ballot(d2 < R2);
            }
#pragma unroll
            for (int u = 0; u < 4; ++u) {
                const unsigned long long m = M[u];
                if (m) {
                    if (cnt == 0) first = base + u * 64 + __builtin_ctzll(m);
                    const bool in = (m >> lane) & 1ull;
                    const int slot = cnt + __popcll(m & ltmask);
                    if (in && slot < NSAMPLE) out[slot] = base + u * 64 + lane;
                    cnt += __popcll(m);
                }
            }
            if (cnt >= NSAMPLE) break;
#pragma unroll
            for (int u = 0; u < 4; ++u) P[u] = Pn[u];
        }
        if (cnt > NSAMPLE) cnt = NSAMPLE;
        if (lane >= cnt && lane < NSAMPLE) out[lane] = (cnt > 0) ? first : 0;
    }
}

// ---------------------------------------------------------------------------
// Kernel 2: fused group — exactly 256 blocks x 1024 threads (1/CU, no tail).
// Feature path: stage (b,c) channel row (64 KB) in LDS; ALL 16 idx4 values
// preloaded into registers before the sync (global loads overlap staging),
// so the gather loop is pure ds_read->store with addresses resident.
// xyz epilogue: each block handles 1024 of the 262144 (b,q,s) samples
// directly from L2 (support 192KB/batch resident), 3 coalesced plane stores.
// ---------------------------------------------------------------------------
__global__ __launch_bounds__(1024) void group_all_kernel(
    const float* __restrict__ query,     // (B, NPOINT, 3)
    const float* __restrict__ support,   // (B, NSUP, 3)
    const float* __restrict__ features,  // (B, NCHAN, NSUP)
    const int*   __restrict__ idx,       // (B, NPOINT*NSAMPLE) flat
    float*       __restrict__ out0,      // (B, 3, NPOINT*NSAMPLE)
    float*       __restrict__ out1)      // (B, NCHAN, NPOINT*NSAMPLE)
{
    __shared__ float lds[NSUP];          // 64 KB
    const int t  = threadIdx.x;
    const int bc = blockIdx.x;           // 0..255 = b*NCHAN + c
    const int b  = bc >> 6;

    // stage channel row (coalesced float4)
    const float4* src4 = reinterpret_cast<const float4*>(features + ((size_t)bc << 14));
    float4* row4 = reinterpret_cast<float4*>(lds);
#pragma unroll
    for (int i = 0; i < 4; ++i)
        row4[i * 1024 + t] = src4[i * 1024 + t];

    // preload all idx4 (issues while staging stores drain)
    const int4* idx4 = reinterpret_cast<const int4*>(idx + ((size_t)b << 16));
    int4 id[16];
#pragma unroll
    for (int k = 0; k < 16; ++k)
        id[k] = idx4[k * 1024 + t];

    __syncthreads();

    // gather + coalesced store
    float4* dst4 = reinterpret_cast<float4*>(out1 + ((size_t)bc << 16));
#pragma unroll
    for (int k = 0; k < 16; ++k) {
        float4 v;
        v.x = lds[id[k].x];
        v.y = lds[id[k].y];
        v.z = lds[id[k].z];
        v.w = lds[id[k].w];
        dst4[k * 1024 + t] = v;
    }

    // xyz epilogue: one sample per thread; g in [0, 262144)
    const int g  = bc * 1024 + t;
    const int bb = g >> 16;
    const int qs = g & (NPOINT * NSAMPLE - 1);
    const int q  = qs >> 5;
    const int sid = idx[g];
    const f3 sp = *reinterpret_cast<const f3*>(support + ((size_t)(bb * NSUP + sid)) * 3);
    const f3 qp = *reinterpret_cast<const f3*>(query + ((size_t)(bb * NPOINT + q)) * 3);
    const size_t obase = ((size_t)bb * 3) * (NPOINT * NSAMPLE) + qs;
    out0[obase]                          = __fsub_rn(sp.x, qp.x);
    out0[obase + NPOINT * NSAMPLE]       = __fsub_rn(sp.y, qp.y);
    out0[obase + 2 * NPOINT * NSAMPLE]   = __fsub_rn(sp.z, qp.z);
}

extern "C" void kernel_launch(void* const* d_in, const int* in_sizes, int n_in,
                              void* d_out, int out_size, void* d_ws, size_t ws_size,
                              hipStream_t stream) {
    const float* query    = (const float*)d_in[0];  // (4,2048,3)
    const float* support  = (const float*)d_in[1];  // (4,16384,3)
    const float* features = (const float*)d_in[2];  // (4,64,16384)

    float* out0 = (float*)d_out;                                 // (4,3,2048,32)
    float* out1 = out0 + (size_t)BATCH * 3 * NPOINT * NSAMPLE;   // (4,64,2048,32)

    const size_t idx_bytes = (size_t)NQ * NSAMPLE * sizeof(int); // 1 MB
    int* ws_idx = (int*)d_ws;
    unsigned int* counter = (unsigned int*)((char*)d_ws + idx_bytes);

    // zero the work-queue head (stream op — graph-capture safe)
    hipMemsetAsync(counter, 0, sizeof(unsigned int), stream);

    // persistent: 1024 blocks x 256 threads = 4096 waves, dynamic queries
    ball_query_kernel<<<1024, 256, 0, stream>>>(query, support, ws_idx, counter);

    // fused grouped_features + grouped_xyz: exactly 256 blocks (1 per CU)
    group_all_kernel<<<BATCH * NCHAN, 1024, 0, stream>>>(
        query, support, features, ws_idx, out0, out1);
}

// Round 18
// 138.504 us; speedup vs baseline: 1.8217x; 1.8217x over previous
//
#include <hip/hip_runtime.h>
#include <hip/hip_bf16.h>

// Problem constants (fixed by setup_inputs)
#define BATCH    4
#define NPOINT   2048
#define NSUP     16384
#define NCHAN    64
#define NSAMPLE  32
#define R2       0.01f   // f32(0.1*0.1) == f32(0.01)
#define NQ       (BATCH * NPOINT)
#define NCELL    1000    // 10x10x10 grid, cell size 0.1

struct f3 { float x, y, z; };

// ---------------------------------------------------------------------------
// Kernel 0: bin build — one 1024-thread block per batch.
// Counting sort of the 16384 support points into 1000 cells (cell = 0.1^3):
// LDS count -> Hillis-Steele exclusive scan -> scatter. Emits bin offsets,
// point ids sorted by cell, AND packed xyz (so ball-query candidate loads
// are contiguous 12B reads). In-cell order is arbitrary (atomic) — the
// bitmask ball query is order-agnostic within candidates.
// ---------------------------------------------------------------------------
__global__ __launch_bounds__(1024) void bin_build_kernel(
    const float* __restrict__ support,   // (B, NSUP, 3)
    unsigned int* __restrict__ off_g,    // (B, 1024)  off[1000] == 16384
    int* __restrict__ sids,              // (B, NSUP)
    float* __restrict__ spts)            // (B, NSUP, 3) packed by cell
{
    __shared__ unsigned int cnt[1024], pfx[1024], cur[1024];
    const int b = blockIdx.x, t = threadIdx.x;
    cnt[t] = 0u;
    __syncthreads();

    const float* sup = support + (size_t)b * NSUP * 3;
    int cells[16];
#pragma unroll
    for (int k = 0; k < 16; ++k) {
        const int pid = k * 1024 + t;
        const float x = sup[pid * 3], y = sup[pid * 3 + 1], z = sup[pid * 3 + 2];
        const int ix = min(9, (int)(x * 10.f));
        const int iy = min(9, (int)(y * 10.f));
        const int iz = min(9, (int)(z * 10.f));
        const int c = (ix * 10 + iy) * 10 + iz;
        cells[k] = c;
        atomicAdd(&cnt[c], 1u);
    }
    __syncthreads();

    pfx[t] = cnt[t];
    __syncthreads();
    for (int s = 1; s < 1024; s <<= 1) {
        const unsigned int v = (t >= s) ? pfx[t - s] : 0u;
        __syncthreads();
        pfx[t] += v;
        __syncthreads();
    }
    const unsigned int exc = pfx[t] - cnt[t];   // exclusive prefix
    cur[t] = exc;
    if (t <= NCELL) off_g[b * 1024 + t] = exc;  // off[1000] = 16384
    __syncthreads();

#pragma unroll
    for (int k = 0; k < 16; ++k) {
        const int pid = k * 1024 + t;
        const unsigned int pos = atomicAdd(&cur[cells[k]], 1u);
        sids[b * NSUP + pos] = pid;
        const float x = sup[pid * 3], y = sup[pid * 3 + 1], z = sup[pid * 3 + 2];
        spts[((size_t)b * NSUP + pos) * 3 + 0] = x;
        spts[((size_t)b * NSUP + pos) * 3 + 1] = y;
        spts[((size_t)b * NSUP + pos) * 3 + 2] = z;
    }
}

// ---------------------------------------------------------------------------
// Kernel 1: ball query via bins + per-query LDS bitmask.
// One wave per query, 8 queries per 512-thread block (waves independent,
// no block barriers). Candidates come from the <=27 neighbor cells
// (<=9 contiguous z-runs, ~440 points avg vs 9000 scanned before).
// Hits set bits in a 512-word bitmask (index order == bit order), then a
// wave-parallel scan (popc + shfl prefix) emits the first 32 set bits in
// index order and pads with the first set bit — exactly the reference
// cumsum-slot semantics, with no early-exit serialization.
// d2 uses explicit _rn ops in reference order ((dx^2+dy^2)+dz^2).
// Cell ranges use +-0.105 margin so float rounding cannot drop a cell.
// ---------------------------------------------------------------------------
__global__ __launch_bounds__(512) void ball_query_kernel(
    const float* __restrict__ query,     // (B, NPOINT, 3)
    const unsigned int* __restrict__ off_g,
    const int* __restrict__ sids,
    const float* __restrict__ spts,
    int* __restrict__ idx_out)           // (B*NPOINT, NSAMPLE)
{
    __shared__ unsigned int mask[8][512];          // 16 KB: 2KB per query
    const int t = threadIdx.x, lane = t & 63, wq = t >> 6;
    const int j = blockIdx.x * 8 + wq;             // query id
    const int b = j >> 11;

    // clear my wave's bitmask region (wave-private, LDS ops in-order per wave)
#pragma unroll
    for (int k = 0; k < 8; ++k) mask[wq][lane * 8 + k] = 0u;

    const float qx = query[j * 3], qy = query[j * 3 + 1], qz = query[j * 3 + 2];
    const int ix0 = max(0, (int)floorf((qx - 0.105f) * 10.f));
    const int ix1 = min(9, (int)floorf((qx + 0.105f) * 10.f));
    const int iy0 = max(0, (int)floorf((qy - 0.105f) * 10.f));
    const int iy1 = min(9, (int)floorf((qy + 0.105f) * 10.f));
    const int iz0 = max(0, (int)floorf((qz - 0.105f) * 10.f));
    const int iz1 = min(9, (int)floorf((qz + 0.105f) * 10.f));

    const unsigned int* off = off_g + b * 1024;
    const int* ids = sids + b * NSUP;
    const float* pts = spts + (size_t)b * NSUP * 3;

    for (int jx = ix0; jx <= ix1; ++jx)
        for (int jy = iy0; jy <= iy1; ++jy) {
            const int c0 = (jx * 10 + jy) * 10 + iz0;
            const int s = off[c0];
            const int e = off[c0 + (iz1 - iz0) + 1];   // z-cells contiguous
            for (int u = s + lane; u < e; u += 64) {
                const float px = pts[u * 3], py = pts[u * 3 + 1], pz = pts[u * 3 + 2];
                const float dx = __fsub_rn(qx, px);
                const float dy = __fsub_rn(qy, py);
                const float dz = __fsub_rn(qz, pz);
                const float d2 = __fadd_rn(
                    __fadd_rn(__fmul_rn(dx, dx), __fmul_rn(dy, dy)),
                    __fmul_rn(dz, dz));
                if (d2 < R2) {
                    const int pid = ids[u];
                    atomicOr(&mask[wq][pid >> 5], 1u << (pid & 31));
                }
            }
        }
    __threadfence_block();   // drain LDS atomics before the scan reads

    // scan: lane holds words 8*lane .. 8*lane+7 (index order across lanes)
    unsigned int w[8];
    int mysum = 0;
#pragma unroll
    for (int k = 0; k < 8; ++k) {
        w[k] = mask[wq][lane * 8 + k];
        mysum += __popc(w[k]);
    }
    int inc = mysum;
#pragma unroll
    for (int o = 1; o < 64; o <<= 1) {
        const int v = __shfl_up(inc, o);
        if (lane >= o) inc += v;
    }
    const int exc = inc - mysum;
    const int total = __shfl(inc, 63);

    const unsigned long long nz = __ballot(mysum != 0);
    int firstLocal = -1;
#pragma unroll
    for (int k = 0; k < 8; ++k)
        if (firstLocal < 0 && w[k])
            firstLocal = ((lane * 8 + k) << 5) + __builtin_ctz(w[k]);
    int first = 0;
    if (nz) first = __shfl(firstLocal, (int)__builtin_ctzll(nz));

    int* out = idx_out + ((size_t)j << 5);
    if (exc < NSAMPLE && mysum > 0) {
        int slot = exc;
#pragma unroll
        for (int k = 0; k < 8; ++k) {
            unsigned int x = w[k];
            while (x && slot < NSAMPLE) {
                const int bb = __builtin_ctz(x);
                x &= x - 1u;
                out[slot++] = ((lane * 8 + k) << 5) + bb;
            }
        }
    }
    const int cnt = min(total, NSAMPLE);
    if (lane >= cnt && lane < NSAMPLE) out[lane] = first;
}

// ---------------------------------------------------------------------------
// Kernel 2: fused group — exactly 256 blocks x 1024 threads (1/CU, no tail).
// UNCHANGED from round 9 (isolate the ball-query change; get its counters).
// ---------------------------------------------------------------------------
__global__ __launch_bounds__(1024) void group_all_kernel(
    const float* __restrict__ query,     // (B, NPOINT, 3)
    const float* __restrict__ support,   // (B, NSUP, 3)
    const float* __restrict__ features,  // (B, NCHAN, NSUP)
    const int*   __restrict__ idx,       // (B, NPOINT*NSAMPLE) flat
    float*       __restrict__ out0,      // (B, 3, NPOINT*NSAMPLE)
    float*       __restrict__ out1)      // (B, NCHAN, NPOINT*NSAMPLE)
{
    __shared__ float lds[NSUP];          // 64 KB
    const int t  = threadIdx.x;
    const int bc = blockIdx.x;           // 0..255 = b*NCHAN + c
    const int b  = bc >> 6;

    const float4* src4 = reinterpret_cast<const float4*>(features + ((size_t)bc << 14));
    float4* row4 = reinterpret_cast<float4*>(lds);
#pragma unroll
    for (int i = 0; i < 4; ++i)
        row4[i * 1024 + t] = src4[i * 1024 + t];

    const int4* idx4 = reinterpret_cast<const int4*>(idx + ((size_t)b << 16));
    int4 id[16];
#pragma unroll
    for (int k = 0; k < 16; ++k)
        id[k] = idx4[k * 1024 + t];

    __syncthreads();

    float4* dst4 = reinterpret_cast<float4*>(out1 + ((size_t)bc << 16));
#pragma unroll
    for (int k = 0; k < 16; ++k) {
        float4 v;
        v.x = lds[id[k].x];
        v.y = lds[id[k].y];
        v.z = lds[id[k].z];
        v.w = lds[id[k].w];
        dst4[k * 1024 + t] = v;
    }

    const int g  = bc * 1024 + t;
    const int bb = g >> 16;
    const int qs = g & (NPOINT * NSAMPLE - 1);
    const int q  = qs >> 5;
    const int sid = idx[g];
    const f3 sp = *reinterpret_cast<const f3*>(support + ((size_t)(bb * NSUP + sid)) * 3);
    const f3 qp = *reinterpret_cast<const f3*>(query + ((size_t)(bb * NPOINT + q)) * 3);
    const size_t obase = ((size_t)bb * 3) * (NPOINT * NSAMPLE) + qs;
    out0[obase]                          = __fsub_rn(sp.x, qp.x);
    out0[obase + NPOINT * NSAMPLE]       = __fsub_rn(sp.y, qp.y);
    out0[obase + 2 * NPOINT * NSAMPLE]   = __fsub_rn(sp.z, qp.z);
}

extern "C" void kernel_launch(void* const* d_in, const int* in_sizes, int n_in,
                              void* d_out, int out_size, void* d_ws, size_t ws_size,
                              hipStream_t stream) {
    const float* query    = (const float*)d_in[0];  // (4,2048,3)
    const float* support  = (const float*)d_in[1];  // (4,16384,3)
    const float* features = (const float*)d_in[2];  // (4,64,16384)

    float* out0 = (float*)d_out;                                 // (4,3,2048,32)
    float* out1 = out0 + (size_t)BATCH * 3 * NPOINT * NSAMPLE;   // (4,64,2048,32)

    // workspace layout
    char* ws = (char*)d_ws;
    int*          ws_idx = (int*)ws;                       // 1 MB
    ws += (size_t)NQ * NSAMPLE * sizeof(int);
    unsigned int* off_g  = (unsigned int*)ws;              // 16 KB
    ws += (size_t)BATCH * 1024 * sizeof(unsigned int);
    int*          sids   = (int*)ws;                       // 256 KB
    ws += (size_t)BATCH * NSUP * sizeof(int);
    float*        spts   = (float*)ws;                     // 768 KB

    // 1) bin the support points (one block per batch)
    bin_build_kernel<<<BATCH, 1024, 0, stream>>>(support, off_g, sids, spts);

    // 2) ball query: 1024 blocks x 512 threads, 8 queries (waves) per block
    ball_query_kernel<<<NQ / 8, 512, 0, stream>>>(query, off_g, sids, spts, ws_idx);

    // 3) fused grouped_features + grouped_xyz: exactly 256 blocks (1 per CU)
    group_all_kernel<<<BATCH * NCHAN, 1024, 0, stream>>>(
        query, support, features, ws_idx, out0, out1);
}